// Round 6
// baseline (1086.401 us; speedup 1.0000x reference)
//
#include <hip/hip_runtime.h>
#include <math.h>

typedef _Float16 f16;
typedef _Float16 h8 __attribute__((ext_vector_type(8)));
typedef float f32x4 __attribute__((ext_vector_type(4)));

#define HEADS 12
#define DH 64
#define DD 768
#define FFD 3072
#define EMBD 300
#define KPAD 320
#define NLAYER 4
#define NB 16
#define NCTX 4096           // 16 * 256
#define NALL 6144           // 16*256 + 16*128

// ---------------- block reduction (sum) ----------------
__device__ __forceinline__ float block_reduce_sum(float v, float* red) {
  #pragma unroll
  for (int o = 32; o; o >>= 1) v += __shfl_xor(v, o);
  const int wid = threadIdx.x >> 6;
  __syncthreads();
  if ((threadIdx.x & 63) == 0) red[wid] = v;
  __syncthreads();
  float r = red[0];
  #pragma unroll
  for (int w = 1; w < 4; ++w) r += red[w];
  return r;
}

// ---------------- async global->LDS 16B ----------------
__device__ __forceinline__ void gload16(const f16* g, f16* lds) {
  __builtin_amdgcn_global_load_lds(
      (const __attribute__((address_space(1))) unsigned int*)g,
      (__attribute__((address_space(3))) unsigned int*)lds, 16, 0, 0);
}

// ---------------- weight transpose + cast (z-batched) ----------------
__launch_bounds__(256)
__global__ void transpose_cast_kernel(const float* __restrict__ W, f16* __restrict__ Wt,
                                      int K, int M, int Kpad,
                                      size_t srcStride, size_t dstStride) {
  W += (size_t)blockIdx.z * srcStride;
  Wt += (size_t)blockIdx.z * dstStride;
  __shared__ float t[32][33];
  const int k0 = blockIdx.x * 32, m0 = blockIdx.y * 32;
  const int c = threadIdx.x & 31, r8 = threadIdx.x >> 5;
  #pragma unroll
  for (int p = 0; p < 4; ++p) {
    const int k = k0 + r8 + p * 8;
    t[r8 + p * 8][c] = (k < K && m0 + c < M) ? W[(size_t)k * M + m0 + c] : 0.f;
  }
  __syncthreads();
  #pragma unroll
  for (int p = 0; p < 4; ++p) {
    const int m = m0 + r8 + p * 8;
    const int k = k0 + c;
    if (m < M && k < Kpad) Wt[(size_t)m * Kpad + k] = (f16)t[c][r8 + p * 8];
  }
}

__launch_bounds__(256)
__global__ void castpad_kernel(const float* __restrict__ ctx, const float* __restrict__ asp,
                               f16* __restrict__ xp) {
  const int tok = blockIdx.x;
  const float* src;
  int r;
  if (tok < NCTX) { src = ctx; r = tok; } else { src = asp; r = tok - NCTX; }
  for (int j = threadIdx.x; j < KPAD; j += 256)
    xp[(size_t)tok * KPAD + j] = (j < EMBD) ? (f16)src[(size_t)r * EMBD + j] : (f16)0.f;
}

__launch_bounds__(256)
__global__ void bias_concat_kernel(const float* __restrict__ bq, const float* __restrict__ bk,
                                   const float* __restrict__ bv, float* __restrict__ bqkv) {
  const int l = blockIdx.x;
  for (int j = threadIdx.x; j < DD; j += 256) {
    bqkv[l * 3 * DD + j] = bq[l * DD + j];
    bqkv[l * 3 * DD + DD + j] = bk[l * DD + j];
    bqkv[l * 3 * DD + 2 * DD + j] = bv[l * DD + j];
  }
}

// ---------------- f16 MFMA GEMM: BK=32 double-buffer, XCD swizzle, opt split-K ----
// C[N,M](f16) = act(A[N,K] @ Bt[M,K]^T + bias). KSPLIT>1: blockIdx.z handles
// K-range z*K/KSPLIT..., writes partial z at C + z*NALL*M (bias only in z=0).
#define GBM 128
#define GBN 128
#define GBK 32

template<int K, int KSPLIT, int ACT>
__launch_bounds__(256)
__global__ void gemm_2ph(const f16* __restrict__ A, const f16* __restrict__ Bt,
                         const float* __restrict__ bias, f16* __restrict__ C, int M) {
  constexpr int KB = K / KSPLIT;
  constexpr int NSTEP = KB / GBK;
  __shared__ __align__(16) f16 As[2][GBM * GBK];
  __shared__ __align__(16) f16 Bs[2][GBN * GBK];
  const int tid = threadIdx.x, lane = tid & 63, wid = tid >> 6;
  const int wr = (wid >> 1) * 64, wc = (wid & 1) * 64;
  const int l15 = lane & 15, lg = lane >> 4;

  // XCD-chunked bijective block swizzle (all grids have nwg % 8 == 0)
  const int gx = gridDim.x;
  const int nwg = gx * gridDim.y;
  int lin = blockIdx.y * gx + blockIdx.x;
  lin = (lin & 7) * (nwg >> 3) + (lin >> 3);
  const int bm = (lin % gx) * GBM;
  const int bn = (lin / gx) * GBN;
  const int kb0 = (KSPLIT > 1) ? blockIdx.z * KB : 0;

  // staging: chunk v = row*4 + s holds global seg (s ^ ((row>>1)&3)); LDS linear.
  const f16* Ag[2]; const f16* Bg[2];
  int ldsOff[2];
  #pragma unroll
  for (int c = 0; c < 2; ++c) {
    const int v = c * 256 + tid;
    const int row = v >> 2, s = v & 3;
    const int gcol = (s ^ ((row >> 1) & 3)) * 8;
    Ag[c] = A + (size_t)(bm + row) * K + kb0 + gcol;
    Bg[c] = Bt + (size_t)(bn + row) * K + kb0 + gcol;
    ldsOff[c] = (c * 256 + wid * 64) * 8;   // wave-uniform; HW adds lane*16B
  }

  f32x4 acc[4][4] = {};

  #pragma unroll
  for (int c = 0; c < 2; ++c) {
    gload16(Ag[c], &As[0][ldsOff[c]]);
    gload16(Bg[c], &Bs[0][ldsOff[c]]);
  }

  int cur = 0;
  for (int t = 0; t < NSTEP; ++t) {
    __syncthreads();            // drains prev-step loads (vmcnt 0), frees other buf
    if (t + 1 < NSTEP) {
      const int kb = (t + 1) * GBK;
      #pragma unroll
      for (int c = 0; c < 2; ++c) {
        gload16(Ag[c] + kb, &As[cur ^ 1][ldsOff[c]]);
        gload16(Bg[c] + kb, &Bs[cur ^ 1][ldsOff[c]]);
      }
    }
    h8 af[4], bf[4];
    #pragma unroll
    for (int m = 0; m < 4; ++m) {
      const int row = wr + m * 16 + l15;
      af[m] = *(const h8*)&As[cur][(row * 4 + (lg ^ ((row >> 1) & 3))) * 8];
    }
    #pragma unroll
    for (int n = 0; n < 4; ++n) {
      const int row = wc + n * 16 + l15;
      bf[n] = *(const h8*)&Bs[cur][(row * 4 + (lg ^ ((row >> 1) & 3))) * 8];
    }
    #pragma unroll
    for (int m = 0; m < 4; ++m)
      #pragma unroll
      for (int n = 0; n < 4; ++n)
        acc[m][n] = __builtin_amdgcn_mfma_f32_16x16x32_f16(af[m], bf[n], acc[m][n], 0, 0, 0);
    cur ^= 1;
  }

  f16* Co = C + ((KSPLIT > 1) ? (size_t)blockIdx.z * NALL * M : (size_t)0);
  #pragma unroll
  for (int m = 0; m < 4; ++m) {
    #pragma unroll
    for (int n = 0; n < 4; ++n) {
      #pragma unroll
      for (int r = 0; r < 4; ++r) {
        const int row = bm + wr + m * 16 + lg * 4 + r;
        const int col = bn + wc + n * 16 + l15;
        float v = acc[m][n][r];
        if (KSPLIT == 1 || blockIdx.z == 0) v += bias[col];
        if (ACT == 1) {
          const float u = 1.5957691216057308f * (v + 0.044715f * v * v * v);
          v = v / (1.f + __expf(-u));
        }
        Co[(size_t)row * M + col] = (f16)v;
      }
    }
  }
}

// ---------------- MFMA attention: one block per (b,h) ----------------
template<int S>
__launch_bounds__(256)
__global__ void attn_mfma_kernel(const f16* __restrict__ qkv, f16* __restrict__ ao, int tokoff) {
  constexpr int KSTR = 88;
  constexpr int VSTR = 264;
  __shared__ __align__(16) f16 Ks[S][KSTR];
  __shared__ __align__(16) f16 Vt[DH][VSTR];
  __shared__ __align__(16) f16 Pl[4][16][VSTR];
  const int b = blockIdx.x / HEADS, h = blockIdx.x % HEADS;
  const int tid = threadIdx.x, lane = tid & 63, wid = tid >> 6;
  const int l15 = lane & 15, lg = lane >> 4;
  const size_t base = (size_t)(tokoff + b * S) * (3 * DD) + (size_t)h * DH;
  const f16* qg = qkv + base;
  const f16* kg = qkv + base + DD;
  const f16* vg = qkv + base + 2 * DD;

  for (int c = tid; c < S * 8; c += 256) {
    const int row = c >> 3, off = (c & 7) * 8;
    *(h8*)&Ks[row][off] = *(const h8*)&kg[(size_t)row * (3 * DD) + off];
    const h8 vv = *(const h8*)&vg[(size_t)row * (3 * DD) + off];
    #pragma unroll
    for (int j = 0; j < 8; ++j) Vt[off + j][row] = vv[j];
  }
  __syncthreads();

  for (int qt = wid; qt < S / 16; qt += 4) {
    const int q0 = qt * 16;
    h8 aq[2];
    #pragma unroll
    for (int s = 0; s < 2; ++s)
      aq[s] = *(const h8*)&qg[(size_t)(q0 + l15) * (3 * DD) + s * 32 + lg * 8];

    f32x4 sc[S / 16];
    #pragma unroll
    for (int kt = 0; kt < S / 16; ++kt) {
      f32x4 c = {};
      const h8 b0 = *(const h8*)&Ks[kt * 16 + l15][lg * 8];
      const h8 b1 = *(const h8*)&Ks[kt * 16 + l15][32 + lg * 8];
      c = __builtin_amdgcn_mfma_f32_16x16x32_f16(aq[0], b0, c, 0, 0, 0);
      c = __builtin_amdgcn_mfma_f32_16x16x32_f16(aq[1], b1, c, 0, 0, 0);
      sc[kt] = c;
    }
    float mx[4], zz[4];
    #pragma unroll
    for (int r = 0; r < 4; ++r) {
      float m = -1e30f;
      #pragma unroll
      for (int kt = 0; kt < S / 16; ++kt) m = fmaxf(m, sc[kt][r]);
      #pragma unroll
      for (int o = 1; o < 16; o <<= 1) m = fmaxf(m, __shfl_xor(m, o));
      mx[r] = m; zz[r] = 0.f;
    }
    #pragma unroll
    for (int kt = 0; kt < S / 16; ++kt)
      #pragma unroll
      for (int r = 0; r < 4; ++r) {
        const float p = __expf((sc[kt][r] - mx[r]) * 0.125f);
        zz[r] += p;
        Pl[wid][lg * 4 + r][kt * 16 + l15] = (f16)p;
      }
    #pragma unroll
    for (int r = 0; r < 4; ++r) {
      #pragma unroll
      for (int o = 1; o < 16; o <<= 1) zz[r] += __shfl_xor(zz[r], o);
      zz[r] = 1.f / zz[r];
    }
    // Pl is wave-private; same-wave LDS ordering, no barrier needed.
    f32x4 o4[4] = {};
    #pragma unroll
    for (int ks = 0; ks < S / 32; ++ks) {
      const h8 pa = *(const h8*)&Pl[wid][l15][ks * 32 + lg * 8];
      #pragma unroll
      for (int n = 0; n < 4; ++n) {
        const h8 bv_ = *(const h8*)&Vt[n * 16 + l15][ks * 32 + lg * 8];
        o4[n] = __builtin_amdgcn_mfma_f32_16x16x32_f16(pa, bv_, o4[n], 0, 0, 0);
      }
    }
    #pragma unroll
    for (int n = 0; n < 4; ++n)
      #pragma unroll
      for (int r = 0; r < 4; ++r) {
        const int row = q0 + lg * 4 + r;
        ao[(size_t)(tokoff + b * S + row) * DD + h * DH + n * 16 + l15] = (f16)(o4[n][r] * zz[r]);
      }
  }
}

// ---------------- fc1-out(f16) + pos_emb + LN -> f16 ----------------
__launch_bounds__(256)
__global__ void pos_ln16(const f16* __restrict__ tmp, const float* __restrict__ pos,
                         const float* __restrict__ g, const float* __restrict__ be,
                         f16* __restrict__ out) {
  __shared__ float red[4];
  const int tok = blockIdx.x;
  const int s = (tok < NCTX) ? (tok & 255) : (tok & 127);
  const size_t row = (size_t)tok * DD;
  float x[3]; float sm = 0.f, ss = 0.f;
  #pragma unroll
  for (int i = 0; i < 3; ++i) {
    const int j = threadIdx.x + (i << 8);
    x[i] = (float)tmp[row + j] + pos[(size_t)s * DD + j];
    sm += x[i]; ss += x[i] * x[i];
  }
  sm = block_reduce_sum(sm, red);
  ss = block_reduce_sum(ss, red);
  const float mean = sm * (1.f / DD);
  const float inv = rsqrtf(ss * (1.f / DD) - mean * mean + 1e-12f);
  #pragma unroll
  for (int i = 0; i < 3; ++i) {
    const int j = threadIdx.x + (i << 8);
    out[row + j] = (f16)((x[i] - mean) * inv * g[j] + be[j]);
  }
}

// ---------------- residual add (1 or 2 deltas) + LN -> f16 ----------------
template<int ND>
__launch_bounds__(256)
__global__ void add_ln16(const f16* __restrict__ hin, const f16* __restrict__ d0,
                         const f16* __restrict__ d1,
                         const float* __restrict__ g, const float* __restrict__ be,
                         f16* __restrict__ out) {
  __shared__ float red[4];
  const size_t row = (size_t)blockIdx.x * DD;
  float x[3]; float sm = 0.f, ss = 0.f;
  #pragma unroll
  for (int i = 0; i < 3; ++i) {
    const int j = threadIdx.x + (i << 8);
    float v = (float)hin[row + j] + (float)d0[row + j];
    if (ND == 2) v += (float)d1[row + j];
    x[i] = v; sm += v; ss += v * v;
  }
  sm = block_reduce_sum(sm, red);
  ss = block_reduce_sum(ss, red);
  const float mean = sm * (1.f / DD);
  const float inv = rsqrtf(ss * (1.f / DD) - mean * mean + 1e-12f);
  #pragma unroll
  for (int i = 0; i < 3; ++i) {
    const int j = threadIdx.x + (i << 8);
    out[row + j] = (f16)((x[i] - mean) * inv * g[j] + be[j]);
  }
}

// ---------------- final cosine reduction ----------------
struct OutsF16 { const f16* p[4]; };

__launch_bounds__(256)
__global__ void invnorm16_kernel(OutsF16 o4, float* __restrict__ invn) {
  __shared__ float red[4];
  const size_t row = (size_t)blockIdx.x * DD;
  float ss = 0.f;
  #pragma unroll
  for (int l = 0; l < 4; ++l)
    #pragma unroll
    for (int i = 0; i < 3; ++i) {
      const float v = (float)o4.p[l][row + threadIdx.x + (i << 8)];
      ss += v * v;
    }
  ss = block_reduce_sum(ss, red);
  if (threadIdx.x == 0) invn[blockIdx.x] = 1.f / fmaxf(sqrtf(ss), 1e-8f);
}

__launch_bounds__(256)
__global__ void normsum16_kernel(OutsF16 o4, const float* __restrict__ invn,
                                 float* __restrict__ accC, float* __restrict__ accA) {
  const int b = blockIdx.x;
  const int l = blockIdx.y / 3;
  const int j = (blockIdx.y % 3) * 256 + threadIdx.x;
  const int pass = blockIdx.z;
  const int S = pass ? 128 : 256;
  const int tb = pass ? (NCTX + b * 128) : (b * 256);
  float* acc = pass ? accA : accC;
  const f16* __restrict__ src = o4.p[l];
  float s = 0.f;
  for (int si = 0; si < S; ++si)
    s = fmaf((float)src[(size_t)(tb + si) * DD + j], invn[tb + si], s);
  acc[(size_t)b * (4 * DD) + (size_t)l * DD + j] = s;
}

__launch_bounds__(256)
__global__ void final_dot_kernel(const float* __restrict__ a, const float* __restrict__ c,
                                 float* __restrict__ out) {
  __shared__ float red[4];
  const size_t base = (size_t)blockIdx.x * (4 * DD);
  float s = 0.f;
  #pragma unroll
  for (int i = 0; i < 12; ++i) {
    const int j = threadIdx.x + (i << 8);
    s = fmaf(a[base + j], c[base + j], s);
  }
  s = block_reduce_sum(s, red);
  if (threadIdx.x == 0) out[blockIdx.x] = s;
}

// ---------------- host orchestration ----------------
extern "C" void kernel_launch(void* const* d_in, const int* in_sizes, int n_in,
                              void* d_out, int out_size, void* d_ws, size_t ws_size,
                              hipStream_t stream) {
  (void)in_sizes; (void)n_in; (void)out_size; (void)ws_size;
  const float* ctx   = (const float*)d_in[0];
  const float* asp   = (const float*)d_in[1];
  const float* fc1_w = (const float*)d_in[2];
  const float* fc1_b = (const float*)d_in[3];
  const float* pos   = (const float*)d_in[4];
  const float* emb_g = (const float*)d_in[5];
  const float* emb_b = (const float*)d_in[6];
  const float* Wq    = (const float*)d_in[7];
  const float* bq    = (const float*)d_in[8];
  const float* Wk    = (const float*)d_in[9];
  const float* bk    = (const float*)d_in[10];
  const float* Wv    = (const float*)d_in[11];
  const float* bv    = (const float*)d_in[12];
  const float* Wo    = (const float*)d_in[13];
  const float* bo    = (const float*)d_in[14];
  const float* ln1g  = (const float*)d_in[15];
  const float* ln1b  = (const float*)d_in[16];
  const float* W1    = (const float*)d_in[17];
  const float* bf1   = (const float*)d_in[18];
  const float* W2    = (const float*)d_in[19];
  const float* bf2   = (const float*)d_in[20];
  const float* ln2g  = (const float*)d_in[21];
  const float* ln2b  = (const float*)d_in[22];
  float* out = (float*)d_out;

  // ---- workspace carving (all-f16 activations) ----
  f16* f = (f16*)d_ws;
  size_t o = 0;
  f16* fc1T  = f + o; o += (size_t)DD * KPAD;
  f16* WqkvT = f + o; o += (size_t)NLAYER * 3 * DD * DD;
  f16* WoT   = f + o; o += (size_t)NLAYER * DD * DD;
  f16* W1T   = f + o; o += (size_t)NLAYER * FFD * DD;
  f16* W2T   = f + o; o += (size_t)NLAYER * DD * FFD;
  f16* R     = f + o; o += (size_t)NALL * FFD;     // alias: xpad | qkv+ao | mid
  f16* tmp16 = f + o; o += (size_t)NALL * DD;
  f16* h0f16 = f + o; o += (size_t)NALL * DD;
  f16* hmf16 = f + o; o += (size_t)NALL * DD;
  f16* pp    = f + o; o += (size_t)2 * NALL * DD;  // split-K partials (Wo, FF2)
  f16* outs16[4];
  for (int l = 0; l < 4; ++l) { outs16[l] = f + o; o += (size_t)NALL * DD; }

  f16* xpad = R;
  f16* qkv  = R;
  f16* ao   = R + (size_t)NALL * 3 * DD;
  f16* mid  = R;

  float* g32 = (float*)(f + o);
  size_t o2 = 0;
  float* bqkv = g32 + o2; o2 += (size_t)NLAYER * 3 * DD;
  float* accC = g32 + o2; o2 += (size_t)NB * 4 * DD;
  float* accA = g32 + o2; o2 += (size_t)NB * 4 * DD;
  float* invn = g32 + o2; o2 += NALL;

  // ---- weight prep (z-batched) ----
  transpose_cast_kernel<<<dim3(KPAD / 32, DD / 32, 1), 256, 0, stream>>>(
      fc1_w, fc1T, EMBD, DD, KPAD, 0, 0);
  transpose_cast_kernel<<<dim3(DD / 32, DD / 32, NLAYER), 256, 0, stream>>>(
      Wq, WqkvT, DD, DD, DD, (size_t)DD * DD, (size_t)3 * DD * DD);
  transpose_cast_kernel<<<dim3(DD / 32, DD / 32, NLAYER), 256, 0, stream>>>(
      Wk, WqkvT + (size_t)DD * DD, DD, DD, DD, (size_t)DD * DD, (size_t)3 * DD * DD);
  transpose_cast_kernel<<<dim3(DD / 32, DD / 32, NLAYER), 256, 0, stream>>>(
      Wv, WqkvT + (size_t)2 * DD * DD, DD, DD, DD, (size_t)DD * DD, (size_t)3 * DD * DD);
  transpose_cast_kernel<<<dim3(DD / 32, DD / 32, NLAYER), 256, 0, stream>>>(
      Wo, WoT, DD, DD, DD, (size_t)DD * DD, (size_t)DD * DD);
  transpose_cast_kernel<<<dim3(DD / 32, FFD / 32, NLAYER), 256, 0, stream>>>(
      W1, W1T, DD, FFD, DD, (size_t)DD * FFD, (size_t)FFD * DD);
  transpose_cast_kernel<<<dim3(FFD / 32, DD / 32, NLAYER), 256, 0, stream>>>(
      W2, W2T, FFD, DD, FFD, (size_t)FFD * DD, (size_t)DD * FFD);
  bias_concat_kernel<<<NLAYER, 256, 0, stream>>>(bq, bk, bv, bqkv);

  // ---- merged encoder over 6144 tokens ----
  castpad_kernel<<<NALL, 256, 0, stream>>>(ctx, asp, xpad);
  gemm_2ph<KPAD, 1, 0><<<dim3(NALL / 128, DD / 128), 256, 0, stream>>>(
      xpad, fc1T, fc1_b, tmp16, DD);
  pos_ln16<<<NALL, 256, 0, stream>>>(tmp16, pos, emb_g, emb_b, h0f16);

  const f16* hin16 = h0f16;
  for (int l = 0; l < NLAYER; ++l) {
    gemm_2ph<DD, 1, 0><<<dim3(NALL / 128, (3 * DD) / 128), 256, 0, stream>>>(
        hin16, WqkvT + (size_t)l * 3 * DD * DD, bqkv + l * 3 * DD, qkv, 3 * DD);
    attn_mfma_kernel<256><<<NB * HEADS, 256, 0, stream>>>(qkv, ao, 0);
    attn_mfma_kernel<128><<<NB * HEADS, 256, 0, stream>>>(qkv, ao, NCTX);
    gemm_2ph<DD, 2, 0><<<dim3(NALL / 128, DD / 128, 2), 256, 0, stream>>>(
        ao, WoT + (size_t)l * DD * DD, bo + l * DD, pp, DD);
    add_ln16<2><<<NALL, 256, 0, stream>>>(hin16, pp, pp + (size_t)NALL * DD,
                                          ln1g + l * DD, ln1b + l * DD, hmf16);
    gemm_2ph<DD, 1, 1><<<dim3(NALL / 128, FFD / 128), 256, 0, stream>>>(
        hmf16, W1T + (size_t)l * FFD * DD, bf1 + l * FFD, mid, FFD);
    gemm_2ph<FFD, 2, 0><<<dim3(NALL / 128, DD / 128, 2), 256, 0, stream>>>(
        mid, W2T + (size_t)l * DD * FFD, bf2 + l * DD, pp, DD);
    add_ln16<2><<<NALL, 256, 0, stream>>>(hmf16, pp, pp + (size_t)NALL * DD,
                                          ln2g + l * DD, ln2b + l * DD, outs16[l]);
    hin16 = outs16[l];
  }

  OutsF16 o4;
  for (int i = 0; i < 4; ++i) o4.p[i] = outs16[i];
  invnorm16_kernel<<<NALL, 256, 0, stream>>>(o4, invn);
  normsum16_kernel<<<dim3(NB, 12, 2), 256, 0, stream>>>(o4, invn, accC, accA);
  final_dot_kernel<<<NB, 256, 0, stream>>>(accA, accC, out);
}

// Round 7
// 1007.727 us; speedup vs baseline: 1.0781x; 1.0781x over previous
//
#include <hip/hip_runtime.h>
#include <math.h>

typedef _Float16 f16;
typedef _Float16 h8 __attribute__((ext_vector_type(8)));
typedef float f32x4 __attribute__((ext_vector_type(4)));

#define HEADS 12
#define DH 64
#define DD 768
#define FFD 3072
#define EMBD 300
#define KPAD 320
#define NLAYER 4
#define NB 16
#define NCTX 4096           // 16 * 256
#define NALL 6144           // 16*256 + 16*128

// ---------------- block reduction (sum) ----------------
__device__ __forceinline__ float block_reduce_sum(float v, float* red) {
  #pragma unroll
  for (int o = 32; o; o >>= 1) v += __shfl_xor(v, o);
  const int wid = threadIdx.x >> 6;
  __syncthreads();
  if ((threadIdx.x & 63) == 0) red[wid] = v;
  __syncthreads();
  float r = red[0];
  #pragma unroll
  for (int w = 1; w < 4; ++w) r += red[w];
  return r;
}

// ---------------- async global->LDS 16B ----------------
__device__ __forceinline__ void gload16(const f16* g, f16* lds) {
  __builtin_amdgcn_global_load_lds(
      (const __attribute__((address_space(1))) unsigned int*)g,
      (__attribute__((address_space(3))) unsigned int*)lds, 16, 0, 0);
}

// ---------------- weight transpose + cast (z-batched) ----------------
__launch_bounds__(256)
__global__ void transpose_cast_kernel(const float* __restrict__ W, f16* __restrict__ Wt,
                                      int K, int M, int Kpad,
                                      size_t srcStride, size_t dstStride) {
  W += (size_t)blockIdx.z * srcStride;
  Wt += (size_t)blockIdx.z * dstStride;
  __shared__ float t[32][33];
  const int k0 = blockIdx.x * 32, m0 = blockIdx.y * 32;
  const int c = threadIdx.x & 31, r8 = threadIdx.x >> 5;
  #pragma unroll
  for (int p = 0; p < 4; ++p) {
    const int k = k0 + r8 + p * 8;
    t[r8 + p * 8][c] = (k < K && m0 + c < M) ? W[(size_t)k * M + m0 + c] : 0.f;
  }
  __syncthreads();
  #pragma unroll
  for (int p = 0; p < 4; ++p) {
    const int m = m0 + r8 + p * 8;
    const int k = k0 + c;
    if (m < M && k < Kpad) Wt[(size_t)m * Kpad + k] = (f16)t[c][r8 + p * 8];
  }
}

__launch_bounds__(256)
__global__ void castpad_kernel(const float* __restrict__ ctx, const float* __restrict__ asp,
                               f16* __restrict__ xp) {
  const int tok = blockIdx.x;
  const float* src;
  int r;
  if (tok < NCTX) { src = ctx; r = tok; } else { src = asp; r = tok - NCTX; }
  for (int j = threadIdx.x; j < KPAD; j += 256)
    xp[(size_t)tok * KPAD + j] = (j < EMBD) ? (f16)src[(size_t)r * EMBD + j] : (f16)0.f;
}

__launch_bounds__(256)
__global__ void bias_concat_kernel(const float* __restrict__ bq, const float* __restrict__ bk,
                                   const float* __restrict__ bv, float* __restrict__ bqkv) {
  const int l = blockIdx.x;
  for (int j = threadIdx.x; j < DD; j += 256) {
    bqkv[l * 3 * DD + j] = bq[l * DD + j];
    bqkv[l * 3 * DD + DD + j] = bk[l * DD + j];
    bqkv[l * 3 * DD + 2 * DD + j] = bv[l * DD + j];
  }
}

// ---------------- f16 MFMA GEMM: 3-buffer 2-ahead pipeline, counted vmcnt ----------
// C[N,M](f16) = act(A[N,K] @ Bt[M,K]^T + bias). KSPLIT>1: blockIdx.z handles a
// K-range and writes partial z at C + z*NALL*M (bias only applied in z=0).
// Per K-step: vmcnt(4) [keep next tile's loads in flight] -> s_barrier ->
// stage tile t+2 -> ds_read + MFMA tile t.  One barrier per step, never a
// full drain in the main loop (T4 counted-vmcnt).
#define GBM 128
#define GBN 128
#define GBK 32

template<int K, int KSPLIT, int ACT>
__launch_bounds__(256)
__global__ void gemm_3buf(const f16* __restrict__ A, const f16* __restrict__ Bt,
                          const float* __restrict__ bias, f16* __restrict__ C, int M) {
  constexpr int KB = K / KSPLIT;
  constexpr int NSTEP = KB / GBK;       // >= 10 for all instantiations
  __shared__ __align__(16) f16 As[3][GBM * GBK];
  __shared__ __align__(16) f16 Bs[3][GBN * GBK];
  const int tid = threadIdx.x, lane = tid & 63, wid = tid >> 6;
  const int wr = (wid >> 1) * 64, wc = (wid & 1) * 64;
  const int l15 = lane & 15, lg = lane >> 4;

  const int bm = blockIdx.x * GBM;
  const int bn = blockIdx.y * GBN;
  const int kb0 = (KSPLIT > 1) ? blockIdx.z * KB : 0;

  // staging: chunk v = row*4 + s holds global seg (s ^ ((row>>1)&3)); LDS linear.
  const f16* Ag[2]; const f16* Bg[2];
  int ldsOff[2];
  #pragma unroll
  for (int c = 0; c < 2; ++c) {
    const int v = c * 256 + tid;
    const int row = v >> 2, s = v & 3;
    const int gcol = (s ^ ((row >> 1) & 3)) * 8;
    Ag[c] = A + (size_t)(bm + row) * K + kb0 + gcol;
    Bg[c] = Bt + (size_t)(bn + row) * K + kb0 + gcol;
    ldsOff[c] = (c * 256 + wid * 64) * 8;   // wave-uniform; HW adds lane*16B
  }

  f32x4 acc[4][4] = {};

  // prologue: stage tiles 0 and 1
  #pragma unroll
  for (int c = 0; c < 2; ++c) {
    gload16(Ag[c], &As[0][ldsOff[c]]);
    gload16(Bg[c], &Bs[0][ldsOff[c]]);
  }
  #pragma unroll
  for (int c = 0; c < 2; ++c) {
    gload16(Ag[c] + GBK, &As[1][ldsOff[c]]);
    gload16(Bg[c] + GBK, &Bs[1][ldsOff[c]]);
  }

  int s3 = 0;        // t % 3
  for (int t = 0; t < NSTEP; ++t) {
    if (t + 1 < NSTEP) asm volatile("s_waitcnt vmcnt(4)" ::: "memory");
    else               asm volatile("s_waitcnt vmcnt(0)" ::: "memory");
    __builtin_amdgcn_s_barrier();
    if (t + 2 < NSTEP) {
      const int sn = (s3 + 2 >= 3) ? s3 - 1 : s3 + 2;
      const int kb = (t + 2) * GBK;
      #pragma unroll
      for (int c = 0; c < 2; ++c) {
        gload16(Ag[c] + kb, &As[sn][ldsOff[c]]);
        gload16(Bg[c] + kb, &Bs[sn][ldsOff[c]]);
      }
    }
    h8 af[4], bf[4];
    #pragma unroll
    for (int m = 0; m < 4; ++m) {
      const int row = wr + m * 16 + l15;
      af[m] = *(const h8*)&As[s3][(row * 4 + (lg ^ ((row >> 1) & 3))) * 8];
    }
    #pragma unroll
    for (int n = 0; n < 4; ++n) {
      const int row = wc + n * 16 + l15;
      bf[n] = *(const h8*)&Bs[s3][(row * 4 + (lg ^ ((row >> 1) & 3))) * 8];
    }
    #pragma unroll
    for (int m = 0; m < 4; ++m)
      #pragma unroll
      for (int n = 0; n < 4; ++n)
        acc[m][n] = __builtin_amdgcn_mfma_f32_16x16x32_f16(af[m], bf[n], acc[m][n], 0, 0, 0);
    s3 = (s3 + 1 >= 3) ? 0 : s3 + 1;
  }

  f16* Co = C + ((KSPLIT > 1) ? (size_t)blockIdx.z * NALL * M : (size_t)0);
  #pragma unroll
  for (int m = 0; m < 4; ++m) {
    #pragma unroll
    for (int n = 0; n < 4; ++n) {
      #pragma unroll
      for (int r = 0; r < 4; ++r) {
        const int row = bm + wr + m * 16 + lg * 4 + r;
        const int col = bn + wc + n * 16 + l15;
        float v = acc[m][n][r];
        if (KSPLIT == 1 || blockIdx.z == 0) v += bias[col];
        if (ACT == 1) {
          const float u = 1.5957691216057308f * (v + 0.044715f * v * v * v);
          v = v / (1.f + __expf(-u));
        }
        Co[(size_t)row * M + col] = (f16)v;
      }
    }
  }
}

// ---------------- MFMA attention: one block per (b,h) ----------------
template<int S>
__launch_bounds__(256)
__global__ void attn_mfma_kernel(const f16* __restrict__ qkv, f16* __restrict__ ao, int tokoff) {
  constexpr int KSTR = 88;
  constexpr int VSTR = 264;
  __shared__ __align__(16) f16 Ks[S][KSTR];
  __shared__ __align__(16) f16 Vt[DH][VSTR];
  __shared__ __align__(16) f16 Pl[4][16][VSTR];
  const int b = blockIdx.x / HEADS, h = blockIdx.x % HEADS;
  const int tid = threadIdx.x, lane = tid & 63, wid = tid >> 6;
  const int l15 = lane & 15, lg = lane >> 4;
  const size_t base = (size_t)(tokoff + b * S) * (3 * DD) + (size_t)h * DH;
  const f16* qg = qkv + base;
  const f16* kg = qkv + base + DD;
  const f16* vg = qkv + base + 2 * DD;

  for (int c = tid; c < S * 8; c += 256) {
    const int row = c >> 3, off = (c & 7) * 8;
    *(h8*)&Ks[row][off] = *(const h8*)&kg[(size_t)row * (3 * DD) + off];
    const h8 vv = *(const h8*)&vg[(size_t)row * (3 * DD) + off];
    #pragma unroll
    for (int j = 0; j < 8; ++j) Vt[off + j][row] = vv[j];
  }
  __syncthreads();

  for (int qt = wid; qt < S / 16; qt += 4) {
    const int q0 = qt * 16;
    h8 aq[2];
    #pragma unroll
    for (int s = 0; s < 2; ++s)
      aq[s] = *(const h8*)&qg[(size_t)(q0 + l15) * (3 * DD) + s * 32 + lg * 8];

    f32x4 sc[S / 16];
    #pragma unroll
    for (int kt = 0; kt < S / 16; ++kt) {
      f32x4 c = {};
      const h8 b0 = *(const h8*)&Ks[kt * 16 + l15][lg * 8];
      const h8 b1 = *(const h8*)&Ks[kt * 16 + l15][32 + lg * 8];
      c = __builtin_amdgcn_mfma_f32_16x16x32_f16(aq[0], b0, c, 0, 0, 0);
      c = __builtin_amdgcn_mfma_f32_16x16x32_f16(aq[1], b1, c, 0, 0, 0);
      sc[kt] = c;
    }
    float mx[4], zz[4];
    #pragma unroll
    for (int r = 0; r < 4; ++r) {
      float m = -1e30f;
      #pragma unroll
      for (int kt = 0; kt < S / 16; ++kt) m = fmaxf(m, sc[kt][r]);
      #pragma unroll
      for (int o = 1; o < 16; o <<= 1) m = fmaxf(m, __shfl_xor(m, o));
      mx[r] = m; zz[r] = 0.f;
    }
    #pragma unroll
    for (int kt = 0; kt < S / 16; ++kt)
      #pragma unroll
      for (int r = 0; r < 4; ++r) {
        const float p = __expf((sc[kt][r] - mx[r]) * 0.125f);
        zz[r] += p;
        Pl[wid][lg * 4 + r][kt * 16 + l15] = (f16)p;
      }
    #pragma unroll
    for (int r = 0; r < 4; ++r) {
      #pragma unroll
      for (int o = 1; o < 16; o <<= 1) zz[r] += __shfl_xor(zz[r], o);
      zz[r] = 1.f / zz[r];
    }
    // Pl is wave-private; same-wave LDS ordering, no barrier needed.
    f32x4 o4[4] = {};
    #pragma unroll
    for (int ks = 0; ks < S / 32; ++ks) {
      const h8 pa = *(const h8*)&Pl[wid][l15][ks * 32 + lg * 8];
      #pragma unroll
      for (int n = 0; n < 4; ++n) {
        const h8 bv_ = *(const h8*)&Vt[n * 16 + l15][ks * 32 + lg * 8];
        o4[n] = __builtin_amdgcn_mfma_f32_16x16x32_f16(pa, bv_, o4[n], 0, 0, 0);
      }
    }
    #pragma unroll
    for (int n = 0; n < 4; ++n)
      #pragma unroll
      for (int r = 0; r < 4; ++r) {
        const int row = q0 + lg * 4 + r;
        ao[(size_t)(tokoff + b * S + row) * DD + h * DH + n * 16 + l15] = (f16)(o4[n][r] * zz[r]);
      }
  }
}

// ---------------- fc1-out(f16) + pos_emb + LN -> f16 ----------------
__launch_bounds__(256)
__global__ void pos_ln16(const f16* __restrict__ tmp, const float* __restrict__ pos,
                         const float* __restrict__ g, const float* __restrict__ be,
                         f16* __restrict__ out) {
  __shared__ float red[4];
  const int tok = blockIdx.x;
  const int s = (tok < NCTX) ? (tok & 255) : (tok & 127);
  const size_t row = (size_t)tok * DD;
  float x[3]; float sm = 0.f, ss = 0.f;
  #pragma unroll
  for (int i = 0; i < 3; ++i) {
    const int j = threadIdx.x + (i << 8);
    x[i] = (float)tmp[row + j] + pos[(size_t)s * DD + j];
    sm += x[i]; ss += x[i] * x[i];
  }
  sm = block_reduce_sum(sm, red);
  ss = block_reduce_sum(ss, red);
  const float mean = sm * (1.f / DD);
  const float inv = rsqrtf(ss * (1.f / DD) - mean * mean + 1e-12f);
  #pragma unroll
  for (int i = 0; i < 3; ++i) {
    const int j = threadIdx.x + (i << 8);
    out[row + j] = (f16)((x[i] - mean) * inv * g[j] + be[j]);
  }
}

// ---------------- residual add (1 or 2 deltas) + LN -> f16 ----------------
template<int ND>
__launch_bounds__(256)
__global__ void add_ln16(const f16* __restrict__ hin, const f16* __restrict__ d0,
                         const f16* __restrict__ d1,
                         const float* __restrict__ g, const float* __restrict__ be,
                         f16* __restrict__ out) {
  __shared__ float red[4];
  const size_t row = (size_t)blockIdx.x * DD;
  float x[3]; float sm = 0.f, ss = 0.f;
  #pragma unroll
  for (int i = 0; i < 3; ++i) {
    const int j = threadIdx.x + (i << 8);
    float v = (float)hin[row + j] + (float)d0[row + j];
    if (ND == 2) v += (float)d1[row + j];
    x[i] = v; sm += v; ss += v * v;
  }
  sm = block_reduce_sum(sm, red);
  ss = block_reduce_sum(ss, red);
  const float mean = sm * (1.f / DD);
  const float inv = rsqrtf(ss * (1.f / DD) - mean * mean + 1e-12f);
  #pragma unroll
  for (int i = 0; i < 3; ++i) {
    const int j = threadIdx.x + (i << 8);
    out[row + j] = (f16)((x[i] - mean) * inv * g[j] + be[j]);
  }
}

// ---------------- final cosine reduction ----------------
struct OutsF16 { const f16* p[4]; };

__launch_bounds__(256)
__global__ void invnorm16_kernel(OutsF16 o4, float* __restrict__ invn) {
  __shared__ float red[4];
  const size_t row = (size_t)blockIdx.x * DD;
  float ss = 0.f;
  #pragma unroll
  for (int l = 0; l < 4; ++l)
    #pragma unroll
    for (int i = 0; i < 3; ++i) {
      const float v = (float)o4.p[l][row + threadIdx.x + (i << 8)];
      ss += v * v;
    }
  ss = block_reduce_sum(ss, red);
  if (threadIdx.x == 0) invn[blockIdx.x] = 1.f / fmaxf(sqrtf(ss), 1e-8f);
}

__launch_bounds__(256)
__global__ void normsum16_kernel(OutsF16 o4, const float* __restrict__ invn,
                                 float* __restrict__ accC, float* __restrict__ accA) {
  const int b = blockIdx.x;
  const int l = blockIdx.y / 3;
  const int j = (blockIdx.y % 3) * 256 + threadIdx.x;
  const int pass = blockIdx.z;
  const int S = pass ? 128 : 256;
  const int tb = pass ? (NCTX + b * 128) : (b * 256);
  float* acc = pass ? accA : accC;
  const f16* __restrict__ src = o4.p[l];
  float s = 0.f;
  for (int si = 0; si < S; ++si)
    s = fmaf((float)src[(size_t)(tb + si) * DD + j], invn[tb + si], s);
  acc[(size_t)b * (4 * DD) + (size_t)l * DD + j] = s;
}

__launch_bounds__(256)
__global__ void final_dot_kernel(const float* __restrict__ a, const float* __restrict__ c,
                                 float* __restrict__ out) {
  __shared__ float red[4];
  const size_t base = (size_t)blockIdx.x * (4 * DD);
  float s = 0.f;
  #pragma unroll
  for (int i = 0; i < 12; ++i) {
    const int j = threadIdx.x + (i << 8);
    s = fmaf(a[base + j], c[base + j], s);
  }
  s = block_reduce_sum(s, red);
  if (threadIdx.x == 0) out[blockIdx.x] = s;
}

// ---------------- host orchestration ----------------
extern "C" void kernel_launch(void* const* d_in, const int* in_sizes, int n_in,
                              void* d_out, int out_size, void* d_ws, size_t ws_size,
                              hipStream_t stream) {
  (void)in_sizes; (void)n_in; (void)out_size; (void)ws_size;
  const float* ctx   = (const float*)d_in[0];
  const float* asp   = (const float*)d_in[1];
  const float* fc1_w = (const float*)d_in[2];
  const float* fc1_b = (const float*)d_in[3];
  const float* pos   = (const float*)d_in[4];
  const float* emb_g = (const float*)d_in[5];
  const float* emb_b = (const float*)d_in[6];
  const float* Wq    = (const float*)d_in[7];
  const float* bq    = (const float*)d_in[8];
  const float* Wk    = (const float*)d_in[9];
  const float* bk    = (const float*)d_in[10];
  const float* Wv    = (const float*)d_in[11];
  const float* bv    = (const float*)d_in[12];
  const float* Wo    = (const float*)d_in[13];
  const float* bo    = (const float*)d_in[14];
  const float* ln1g  = (const float*)d_in[15];
  const float* ln1b  = (const float*)d_in[16];
  const float* W1    = (const float*)d_in[17];
  const float* bf1   = (const float*)d_in[18];
  const float* W2    = (const float*)d_in[19];
  const float* bf2   = (const float*)d_in[20];
  const float* ln2g  = (const float*)d_in[21];
  const float* ln2b  = (const float*)d_in[22];
  float* out = (float*)d_out;

  // ---- workspace carving (all-f16 activations) ----
  f16* f = (f16*)d_ws;
  size_t o = 0;
  f16* fc1T  = f + o; o += (size_t)DD * KPAD;
  f16* WqkvT = f + o; o += (size_t)NLAYER * 3 * DD * DD;
  f16* WoT   = f + o; o += (size_t)NLAYER * DD * DD;
  f16* W1T   = f + o; o += (size_t)NLAYER * FFD * DD;
  f16* W2T   = f + o; o += (size_t)NLAYER * DD * FFD;
  f16* R     = f + o; o += (size_t)NALL * FFD;     // alias: xpad | qkv+ao | mid
  f16* tmp16 = f + o; o += (size_t)NALL * DD;
  f16* h0f16 = f + o; o += (size_t)NALL * DD;
  f16* hmf16 = f + o; o += (size_t)NALL * DD;
  f16* pp    = f + o; o += (size_t)2 * NALL * DD;  // split-K partials (Wo, FF2)
  f16* outs16[4];
  for (int l = 0; l < 4; ++l) { outs16[l] = f + o; o += (size_t)NALL * DD; }

  f16* xpad = R;
  f16* qkv  = R;
  f16* ao   = R + (size_t)NALL * 3 * DD;
  f16* mid  = R;

  float* g32 = (float*)(f + o);
  size_t o2 = 0;
  float* bqkv = g32 + o2; o2 += (size_t)NLAYER * 3 * DD;
  float* accC = g32 + o2; o2 += (size_t)NB * 4 * DD;
  float* accA = g32 + o2; o2 += (size_t)NB * 4 * DD;
  float* invn = g32 + o2; o2 += NALL;

  // ---- weight prep (z-batched) ----
  transpose_cast_kernel<<<dim3(KPAD / 32, DD / 32, 1), 256, 0, stream>>>(
      fc1_w, fc1T, EMBD, DD, KPAD, 0, 0);
  transpose_cast_kernel<<<dim3(DD / 32, DD / 32, NLAYER), 256, 0, stream>>>(
      Wq, WqkvT, DD, DD, DD, (size_t)DD * DD, (size_t)3 * DD * DD);
  transpose_cast_kernel<<<dim3(DD / 32, DD / 32, NLAYER), 256, 0, stream>>>(
      Wk, WqkvT + (size_t)DD * DD, DD, DD, DD, (size_t)DD * DD, (size_t)3 * DD * DD);
  transpose_cast_kernel<<<dim3(DD / 32, DD / 32, NLAYER), 256, 0, stream>>>(
      Wv, WqkvT + (size_t)2 * DD * DD, DD, DD, DD, (size_t)DD * DD, (size_t)3 * DD * DD);
  transpose_cast_kernel<<<dim3(DD / 32, DD / 32, NLAYER), 256, 0, stream>>>(
      Wo, WoT, DD, DD, DD, (size_t)DD * DD, (size_t)DD * DD);
  transpose_cast_kernel<<<dim3(DD / 32, FFD / 32, NLAYER), 256, 0, stream>>>(
      W1, W1T, DD, FFD, DD, (size_t)DD * FFD, (size_t)FFD * DD);
  transpose_cast_kernel<<<dim3(FFD / 32, DD / 32, NLAYER), 256, 0, stream>>>(
      W2, W2T, FFD, DD, FFD, (size_t)FFD * DD, (size_t)DD * FFD);
  bias_concat_kernel<<<NLAYER, 256, 0, stream>>>(bq, bk, bv, bqkv);

  // ---- merged encoder over 6144 tokens ----
  castpad_kernel<<<NALL, 256, 0, stream>>>(ctx, asp, xpad);
  gemm_3buf<KPAD, 1, 0><<<dim3(NALL / 128, DD / 128), 256, 0, stream>>>(
      xpad, fc1T, fc1_b, tmp16, DD);
  pos_ln16<<<NALL, 256, 0, stream>>>(tmp16, pos, emb_g, emb_b, h0f16);

  const f16* hin16 = h0f16;
  for (int l = 0; l < NLAYER; ++l) {
    gemm_3buf<DD, 1, 0><<<dim3(NALL / 128, (3 * DD) / 128), 256, 0, stream>>>(
        hin16, WqkvT + (size_t)l * 3 * DD * DD, bqkv + l * 3 * DD, qkv, 3 * DD);
    attn_mfma_kernel<256><<<NB * HEADS, 256, 0, stream>>>(qkv, ao, 0);
    attn_mfma_kernel<128><<<NB * HEADS, 256, 0, stream>>>(qkv, ao, NCTX);
    gemm_3buf<DD, 2, 0><<<dim3(NALL / 128, DD / 128, 2), 256, 0, stream>>>(
        ao, WoT + (size_t)l * DD * DD, bo + l * DD, pp, DD);
    add_ln16<2><<<NALL, 256, 0, stream>>>(hin16, pp, pp + (size_t)NALL * DD,
                                          ln1g + l * DD, ln1b + l * DD, hmf16);
    gemm_3buf<DD, 1, 1><<<dim3(NALL / 128, FFD / 128), 256, 0, stream>>>(
        hmf16, W1T + (size_t)l * FFD * DD, bf1 + l * FFD, mid, FFD);
    gemm_3buf<FFD, 2, 0><<<dim3(NALL / 128, DD / 128, 2), 256, 0, stream>>>(
        mid, W2T + (size_t)l * DD * FFD, bf2 + l * DD, pp, DD);
    add_ln16<2><<<NALL, 256, 0, stream>>>(hmf16, pp, pp + (size_t)NALL * DD,
                                          ln2g + l * DD, ln2b + l * DD, outs16[l]);
    hin16 = outs16[l];
  }

  OutsF16 o4;
  for (int i = 0; i < 4; ++i) o4.p[i] = outs16[i];
  invnorm16_kernel<<<NALL, 256, 0, stream>>>(o4, invn);
  normsum16_kernel<<<dim3(NB, 12, 2), 256, 0, stream>>>(o4, invn, accC, accA);
  final_dot_kernel<<<NB, 256, 0, stream>>>(accA, accC, out);
}